// Round 11
// baseline (348.682 us; speedup 1.0000x reference)
//
#include <hip/hip_runtime.h>

#define CH   1024
#define NPTS 80
#define NEG  0.2f
#define INVTEMP 40.0f

typedef __attribute__((ext_vector_type(8))) short short8;
typedef __attribute__((ext_vector_type(4))) float f32x4;

// Split f32 into hi/lo bf16 (RNE). x ~= hi + lo with relative error ~2^-17.
__device__ __forceinline__ void bsplit(float x, short& hs, short& ls) {
  unsigned u = __builtin_bit_cast(unsigned, x);
  unsigned hb = (u + 0x7fffu + ((u >> 16) & 1u)) >> 16;
  float hf = __builtin_bit_cast(float, hb << 16);
  float r = x - hf;
  unsigned u2 = __builtin_bit_cast(unsigned, r);
  hs = (short)hb;
  ls = (short)((u2 + 0x7fffu + ((u2 >> 16) & 1u)) >> 16);
}

__device__ __forceinline__ float leaky(float v) { return v >= 0.f ? v : NEG * v; }

// Async global->LDS DMA, 16 B per lane. LDS dest wave-uniform base.
__device__ __forceinline__ void dma16(const void* g, void* l) {
  __builtin_amdgcn_global_load_lds(
      (const __attribute__((address_space(1))) unsigned*)g,
      (__attribute__((address_space(3))) unsigned*)l,
      16, 0, 0);
}

// ======================= Pipeline (4 kernels) =======================
// K1: Gram partials. grid = 4 slices x 256 batches, 256 thr (4 waves),
// 66 KB LDS -> 2 blocks/CU (cross-block DMA/compute overlap).
// Each block: 256 ch of one batch in 2 DMA-staged chunks of 128 ch.
__launch_bounds__(256, 2)
__global__ void k1_gram(const float* __restrict__ x, float* __restrict__ Gpart) {
  __shared__ __align__(16) float xstage[128 * 80];   // 40 KB
  __shared__ float G[80][81];                        // 25.9 KB
  const int tid  = threadIdx.x;
  const int lane = tid & 63;
  const int wv   = tid >> 6;        // 0..3
  const int l15  = lane & 15;
  const int g    = lane >> 4;
  const int slice = blockIdx.x & 3;
  const int b     = blockIdx.x >> 2;
  const float* __restrict__ xb = x + (size_t)b * (CH * NPTS);

  for (int i = tid; i < 80 * 81; i += 256) (&G[0][0])[i] = 0.f;

  f32x4 acc[5][5];
  #pragma unroll
  for (int i = 0; i < 5; ++i)
    #pragma unroll
    for (int j = 0; j < 5; ++j) acc[i][j] = (f32x4){0.f, 0.f, 0.f, 0.f};

  for (int chunk = 0; chunk < 2; ++chunk) {
    const char* gsrc = (const char*)(xb + (size_t)(slice * 256 + chunk * 128) * NPTS);
    char* lbase = (char*)xstage;
    #pragma unroll
    for (int i = 0; i < 10; ++i) {
      const int off = (wv * 10 + i) * 1024;
      dma16(gsrc + off + lane * 16, lbase + off);
    }
    __syncthreads();   // vmcnt(0) drain: staged chunk visible (also covers G init)

    // wave wv owns k-step [wv*32, wv*32+32) of this chunk
    short8 fh[5], fl[5];
    const int cbase = wv * 32 + g * 8;
    #pragma unroll
    for (int t = 0; t < 5; ++t) {
      const int n = 16 * t + l15;
      #pragma unroll
      for (int j = 0; j < 8; ++j) {
        short hs, ls2;
        bsplit(xstage[(cbase + j) * 80 + n], hs, ls2);
        fh[t][j] = hs; fl[t][j] = ls2;
      }
    }
    __syncthreads();   // reads done; next chunk DMA may overwrite

    #pragma unroll
    for (int tn = 0; tn < 5; ++tn)
      #pragma unroll
      for (int tm = 0; tm < 5; ++tm) {
        acc[tn][tm] = __builtin_amdgcn_mfma_f32_16x16x32_bf16(fh[tn], fh[tm], acc[tn][tm], 0, 0, 0);
        acc[tn][tm] = __builtin_amdgcn_mfma_f32_16x16x32_bf16(fh[tn], fl[tm], acc[tn][tm], 0, 0, 0);
        acc[tn][tm] = __builtin_amdgcn_mfma_f32_16x16x32_bf16(fl[tn], fh[tm], acc[tn][tm], 0, 0, 0);
      }
  }

  #pragma unroll
  for (int tn = 0; tn < 5; ++tn)
    #pragma unroll
    for (int tm = 0; tm < 5; ++tm)
      #pragma unroll
      for (int r = 0; r < 4; ++r)
        atomicAdd(&G[16 * tn + 4 * g + r][16 * tm + l15], acc[tn][tm][r]);
  __syncthreads();

  float* __restrict__ gp = Gpart + ((size_t)slice * 256 + b) * 6400;
  for (int i = tid; i < 6400; i += 256) gp[i] = G[i / 80][i % 80];
}

// K2: reduce 4 partials, normalize -> adj bf16 hi/lo planes [2][80][104]
// (zero-padded n>=80), zero score accumulator. grid = 256.
__launch_bounds__(256)
__global__ void k2_adj(const float* __restrict__ Gpart,
                       unsigned short* __restrict__ adjws,
                       float* __restrict__ s_ws) {
  __shared__ float Gs[80][80];
  __shared__ float rn[80];
  const int tid = threadIdx.x;
  const int b = blockIdx.x;
  if (tid < 80) s_ws[b * 80 + tid] = 0.f;
  for (int i = tid; i < 6400; i += 256) {
    float v = 0.f;
    #pragma unroll
    for (int sl = 0; sl < 4; ++sl)
      v += Gpart[((size_t)sl * 256 + b) * 6400 + i];
    (&Gs[0][0])[i] = v;
  }
  __syncthreads();
  if (tid < 80) rn[tid] = 1.0f / fmaxf(sqrtf(Gs[tid][tid]), 1e-12f);
  __syncthreads();
  unsigned short* __restrict__ ab = adjws + (size_t)b * 16640;
  for (int i = tid; i < 16640; i += 256) {
    const int p = i / 8320;
    const int r = i - p * 8320;
    const int m = r / 104;
    const int n = r - m * 104;
    float v = (n < 80) ? Gs[m][n] * (rn[m] * rn[n]) : 0.f;
    short hs, ls2; bsplit(v, hs, ls2);
    ab[i] = (unsigned short)(p ? ls2 : hs);
  }
}

// K3: h = X @ adj fused leaky + w-reduce. grid = 8 slices x 256 batches,
// 256 thr (4 waves), 75 KB LDS -> 2 blocks/CU. x slice DMA-staged (L3-hot).
__launch_bounds__(256, 2)
__global__ void k3_gemm2(const float* __restrict__ x,
                         const unsigned short* __restrict__ adjws,
                         const float* __restrict__ w,
                         float* __restrict__ s_ws) {
  __shared__ __align__(16) short adjlds[16640];      // [2][80][104] 33.3 KB
  __shared__ __align__(16) float xstage[128 * 80];   // 40 KB
  __shared__ float wl[128];
  __shared__ float ssc[80];
  const int tid  = threadIdx.x;
  const int lane = tid & 63;
  const int wv   = tid >> 6;        // 0..3
  const int l15  = lane & 15;
  const int g    = lane >> 4;
  const int slice = blockIdx.x & 7;
  const int b     = blockIdx.x >> 3;
  const float* __restrict__ xb = x + (size_t)b * (CH * NPTS);

  // stage adj (L3-hot, coalesced short8)
  {
    const short8* __restrict__ src = (const short8*)(adjws + (size_t)b * 16640);
    short8* __restrict__ dst = (short8*)adjlds;
    for (int i = tid; i < 2080; i += 256) dst[i] = src[i];
  }
  if (tid < 128) wl[tid] = w[slice * 128 + tid];
  if (tid < 80) ssc[tid] = 0.f;
  // DMA x slice: 128 ch x 80 x 4B = 40 KB
  {
    const char* gsrc = (const char*)(xb + (size_t)slice * 128 * NPTS);
    char* lbase = (char*)xstage;
    #pragma unroll
    for (int i = 0; i < 10; ++i) {
      const int off = (wv * 10 + i) * 1024;
      dma16(gsrc + off + lane * 16, lbase + off);
    }
  }
  __syncthreads();

  short (*adjh)[104] = (short (*)[104])adjlds;
  short (*adjl)[104] = (short (*)[104])(adjlds + 8320);

  f32x4 hacc[2][5];
  #pragma unroll
  for (int i = 0; i < 2; ++i)
    #pragma unroll
    for (int j = 0; j < 5; ++j) hacc[i][j] = (f32x4){0.f, 0.f, 0.f, 0.f};

  for (int ksn = 0; ksn < 3; ++ksn) {
    const int nb = 32 * ksn + 8 * g;
    short8 bh[5], bl[5];
    #pragma unroll
    for (int tm = 0; tm < 5; ++tm) {
      bh[tm] = *reinterpret_cast<const short8*>(&adjh[16 * tm + l15][nb]);
      bl[tm] = *reinterpret_cast<const short8*>(&adjl[16 * tm + l15][nb]);
    }
    #pragma unroll
    for (int ct = 0; ct < 2; ++ct) {
      const int row = (wv * 2 + ct) * 16 + l15;   // channel row within slice
      short8 ah, al;
      if (nb < 80) {
        const float* p = &xstage[row * 80 + nb];
        f32x4 va = *reinterpret_cast<const f32x4*>(p);
        f32x4 vb = *reinterpret_cast<const f32x4*>(p + 4);
        #pragma unroll
        for (int j = 0; j < 4; ++j) { short hs, ls2; bsplit(va[j], hs, ls2); ah[j] = hs; al[j] = ls2; }
        #pragma unroll
        for (int j = 0; j < 4; ++j) { short hs, ls2; bsplit(vb[j], hs, ls2); ah[4 + j] = hs; al[4 + j] = ls2; }
      } else {
        ah = (short8){0,0,0,0,0,0,0,0};
        al = (short8){0,0,0,0,0,0,0,0};
      }
      #pragma unroll
      for (int tm = 0; tm < 5; ++tm) {
        hacc[ct][tm] = __builtin_amdgcn_mfma_f32_16x16x32_bf16(ah, bh[tm], hacc[ct][tm], 0, 0, 0);
        hacc[ct][tm] = __builtin_amdgcn_mfma_f32_16x16x32_bf16(ah, bl[tm], hacc[ct][tm], 0, 0, 0);
        hacc[ct][tm] = __builtin_amdgcn_mfma_f32_16x16x32_bf16(al, bh[tm], hacc[ct][tm], 0, 0, 0);
      }
    }
  }

  float sp[5] = {0.f, 0.f, 0.f, 0.f, 0.f};
  #pragma unroll
  for (int ct = 0; ct < 2; ++ct) {
    const int cbl = (wv * 2 + ct) * 16 + 4 * g;
    #pragma unroll
    for (int r = 0; r < 4; ++r) {
      const float wc = wl[cbl + r];
      #pragma unroll
      for (int tm = 0; tm < 5; ++tm) sp[tm] += leaky(hacc[ct][tm][r]) * wc;
    }
  }
  #pragma unroll
  for (int tm = 0; tm < 5; ++tm) {
    float v = sp[tm];
    v += __shfl_xor(v, 16);
    v += __shfl_xor(v, 32);
    if (g == 0) atomicAdd(&ssc[16 * tm + l15], v);
  }
  __syncthreads();
  if (tid < 80) atomicAdd(&s_ws[b * 80 + tid], ssc[tid]);
}

// K4: per-block redundant softmax + streaming scale. grid = 256 x 8, 256 thr.
__launch_bounds__(256)
__global__ void k4_scale(const float* __restrict__ x,
                         const float* __restrict__ s_ws,
                         const float* __restrict__ bias,
                         float* __restrict__ out) {
  __shared__ float att[80];
  __shared__ f32x4 attnv[20];
  const int tid   = threadIdx.x;
  const int b     = blockIdx.x >> 3;
  const int chunk = blockIdx.x & 7;

  if (tid < 64) {
    const int lane = tid;
    const float b0 = bias[0];
    float v0 = leaky(s_ws[b * 80 + lane] + b0) * INVTEMP;
    float v1 = -3.0e38f;
    if (lane < 16) v1 = leaky(s_ws[b * 80 + 64 + lane] + b0) * INVTEMP;
    float mx = fmaxf(v0, v1);
    #pragma unroll
    for (int off = 32; off >= 1; off >>= 1) mx = fmaxf(mx, __shfl_xor(mx, off));
    float e0 = expf(v0 - mx);
    float e1 = (lane < 16) ? expf(v1 - mx) : 0.f;
    float sum = e0 + e1;
    #pragma unroll
    for (int off = 32; off >= 1; off >>= 1) sum += __shfl_xor(sum, off);
    const float inv = 1.0f / sum;
    att[lane] = e0 * inv + 1.0f;
    if (lane < 16) att[64 + lane] = e1 * inv + 1.0f;
  }
  __syncthreads();
  if (tid < 20) {
    f32x4 a = { att[4 * tid], att[4 * tid + 1], att[4 * tid + 2], att[4 * tid + 3] };
    attnv[tid] = a;
  }
  __syncthreads();

  const f32x4* __restrict__ xv = reinterpret_cast<const f32x4*>(x + (size_t)b * (CH * NPTS));
  f32x4* __restrict__ ov = reinterpret_cast<f32x4*>(out + (size_t)b * (CH * NPTS));
  #pragma unroll
  for (int k = 0; k < 10; ++k) {
    const int e4 = chunk * 2560 + k * 256 + tid;
    f32x4 v = xv[e4];
    f32x4 a = attnv[e4 % 20];
    v[0] *= a[0]; v[1] *= a[1]; v[2] *= a[2]; v[3] *= a[3];
    ov[e4] = v;
  }
}

// =================== Fallback: proven round-10 path ===================
__launch_bounds__(512, 1)
__global__ void scgcn_main_kernel(const float* __restrict__ x,
                                  const float* __restrict__ w,
                                  const float* __restrict__ bias,
                                  float* __restrict__ attn_ws) {
  __shared__ __align__(16) float xstage[256 * 80];
  __shared__ float G[80][81];
  __shared__ float rn[80];
  __shared__ float ssc[80];
  __shared__ float wl[CH];
  __shared__ __align__(16) short adjh[80][104];
  __shared__ __align__(16) short adjl[80][104];

  const int tid  = threadIdx.x;
  const int lane = tid & 63;
  const int wv   = tid >> 6;
  const int l15  = lane & 15;
  const int g    = lane >> 4;
  const int b    = blockIdx.x;
  const float* __restrict__ xb = x + (size_t)b * (CH * NPTS);

  for (int i = tid; i < 80 * 81; i += 512) (&G[0][0])[i] = 0.f;
  if (tid < 80) ssc[tid] = 0.f;
  for (int i = tid; i < CH; i += 512) wl[i] = w[i];

  f32x4 acc[5][5];
  #pragma unroll
  for (int i = 0; i < 5; ++i)
    #pragma unroll
    for (int j = 0; j < 5; ++j) acc[i][j] = (f32x4){0.f, 0.f, 0.f, 0.f};

  for (int chunk = 0; chunk < 4; ++chunk) {
    {
      const char* gsrc = (const char*)(xb + (size_t)chunk * 256 * NPTS);
      char* lbase = (char*)xstage;
      #pragma unroll
      for (int i = 0; i < 10; ++i) {
        const int off = (wv * 10 + i) * 1024;
        dma16(gsrc + off + lane * 16, lbase + off);
      }
    }
    __syncthreads();
    short8 fh[5], fl[5];
    const int cbase = wv * 32 + g * 8;
    #pragma unroll
    for (int t = 0; t < 5; ++t) {
      const int n = 16 * t + l15;
      #pragma unroll
      for (int j = 0; j < 8; ++j) {
        short hs, ls2;
        bsplit(xstage[(cbase + j) * 80 + n], hs, ls2);
        fh[t][j] = hs; fl[t][j] = ls2;
      }
    }
    __syncthreads();
    #pragma unroll
    for (int tn = 0; tn < 5; ++tn)
      #pragma unroll
      for (int tm = 0; tm < 5; ++tm) {
        acc[tn][tm] = __builtin_amdgcn_mfma_f32_16x16x32_bf16(fh[tn], fh[tm], acc[tn][tm], 0, 0, 0);
        acc[tn][tm] = __builtin_amdgcn_mfma_f32_16x16x32_bf16(fh[tn], fl[tm], acc[tn][tm], 0, 0, 0);
        acc[tn][tm] = __builtin_amdgcn_mfma_f32_16x16x32_bf16(fl[tn], fh[tm], acc[tn][tm], 0, 0, 0);
      }
  }
  __syncthreads();
  #pragma unroll
  for (int tn = 0; tn < 5; ++tn)
    #pragma unroll
    for (int tm = 0; tm < 5; ++tm)
      #pragma unroll
      for (int r = 0; r < 4; ++r)
        atomicAdd(&G[16 * tn + 4 * g + r][16 * tm + l15], acc[tn][tm][r]);
  __syncthreads();

  if (tid < 80) rn[tid] = 1.0f / fmaxf(sqrtf(G[tid][tid]), 1e-12f);
  __syncthreads();
  for (int i = tid; i < 80 * 104; i += 512) {
    const int m = i / 104;
    const int n = i - m * 104;
    float v = (n < 80) ? G[n][m] * (rn[n] * rn[m]) : 0.f;
    short hs, ls2; bsplit(v, hs, ls2);
    adjh[m][n] = hs; adjl[m][n] = ls2;
  }
  __syncthreads();

  float sp[5] = {0.f, 0.f, 0.f, 0.f, 0.f};
  for (int chunk = 0; chunk < 4; ++chunk) {
    {
      const char* gsrc = (const char*)(xb + (size_t)chunk * 256 * NPTS);
      char* lbase = (char*)xstage;
      #pragma unroll
      for (int i = 0; i < 10; ++i) {
        const int off = (wv * 10 + i) * 1024;
        dma16(gsrc + off + lane * 16, lbase + off);
      }
    }
    __syncthreads();
    f32x4 hacc[2][5];
    #pragma unroll
    for (int i = 0; i < 2; ++i)
      #pragma unroll
      for (int j = 0; j < 5; ++j) hacc[i][j] = (f32x4){0.f, 0.f, 0.f, 0.f};
    for (int ksn = 0; ksn < 3; ++ksn) {
      const int nb = 32 * ksn + 8 * g;
      short8 bh[5], bl[5];
      #pragma unroll
      for (int tm = 0; tm < 5; ++tm) {
        bh[tm] = *reinterpret_cast<const short8*>(&adjh[16 * tm + l15][nb]);
        bl[tm] = *reinterpret_cast<const short8*>(&adjl[16 * tm + l15][nb]);
      }
      #pragma unroll
      for (int ct = 0; ct < 2; ++ct) {
        const int row = (wv * 2 + ct) * 16 + l15;
        short8 ah, al;
        if (nb < 80) {
          const float* p = &xstage[row * 80 + nb];
          f32x4 va = *reinterpret_cast<const f32x4*>(p);
          f32x4 vb = *reinterpret_cast<const f32x4*>(p + 4);
          #pragma unroll
          for (int j = 0; j < 4; ++j) { short hs, ls2; bsplit(va[j], hs, ls2); ah[j] = hs; al[j] = ls2; }
          #pragma unroll
          for (int j = 0; j < 4; ++j) { short hs, ls2; bsplit(vb[j], hs, ls2); ah[4 + j] = hs; al[4 + j] = ls2; }
        } else {
          ah = (short8){0,0,0,0,0,0,0,0};
          al = (short8){0,0,0,0,0,0,0,0};
        }
        #pragma unroll
        for (int tm = 0; tm < 5; ++tm) {
          hacc[ct][tm] = __builtin_amdgcn_mfma_f32_16x16x32_bf16(ah, bh[tm], hacc[ct][tm], 0, 0, 0);
          hacc[ct][tm] = __builtin_amdgcn_mfma_f32_16x16x32_bf16(ah, bl[tm], hacc[ct][tm], 0, 0, 0);
          hacc[ct][tm] = __builtin_amdgcn_mfma_f32_16x16x32_bf16(al, bh[tm], hacc[ct][tm], 0, 0, 0);
        }
      }
    }
    #pragma unroll
    for (int ct = 0; ct < 2; ++ct) {
      const int cb = chunk * 256 + (wv * 2 + ct) * 16 + 4 * g;
      #pragma unroll
      for (int r = 0; r < 4; ++r) {
        const float wc = wl[cb + r];
        #pragma unroll
        for (int tm = 0; tm < 5; ++tm) sp[tm] += leaky(hacc[ct][tm][r]) * wc;
      }
    }
    __syncthreads();
  }
  #pragma unroll
  for (int tm = 0; tm < 5; ++tm) {
    float v = sp[tm];
    v += __shfl_xor(v, 16);
    v += __shfl_xor(v, 32);
    if (g == 0) atomicAdd(&ssc[16 * tm + l15], v);
  }
  __syncthreads();
  if (wv == 0) {
    const float b0 = bias[0];
    float v0 = leaky(ssc[lane] + b0) * INVTEMP;
    float v1 = -3.0e38f;
    if (lane < 16) v1 = leaky(ssc[64 + lane] + b0) * INVTEMP;
    float mx = fmaxf(v0, v1);
    #pragma unroll
    for (int off = 32; off >= 1; off >>= 1) mx = fmaxf(mx, __shfl_xor(mx, off));
    float e0 = expf(v0 - mx);
    float e1 = (lane < 16) ? expf(v1 - mx) : 0.f;
    float sum = e0 + e1;
    #pragma unroll
    for (int off = 32; off >= 1; off >>= 1) sum += __shfl_xor(sum, off);
    const float inv = 1.0f / sum;
    attn_ws[b * 80 + lane] = e0 * inv + 1.0f;
    if (lane < 16) attn_ws[b * 80 + 64 + lane] = e1 * inv + 1.0f;
  }
}

__launch_bounds__(256)
__global__ void scgcn_scale_kernel(const float* __restrict__ x,
                                   const float* __restrict__ attn_ws,
                                   float* __restrict__ out) {
  __shared__ f32x4 attnv[20];
  const int tid   = threadIdx.x;
  const int b     = blockIdx.x >> 3;
  const int chunk = blockIdx.x & 7;
  if (tid < 20) attnv[tid] = reinterpret_cast<const f32x4*>(attn_ws + b * 80)[tid];
  __syncthreads();
  const f32x4* __restrict__ xv = reinterpret_cast<const f32x4*>(x + (size_t)b * (CH * NPTS));
  f32x4* __restrict__ ov = reinterpret_cast<f32x4*>(out + (size_t)b * (CH * NPTS));
  #pragma unroll
  for (int k = 0; k < 10; ++k) {
    const int e4 = chunk * 2560 + k * 256 + tid;
    f32x4 v = xv[e4];
    f32x4 a = attnv[e4 % 20];
    v[0] *= a[0]; v[1] *= a[1]; v[2] *= a[2]; v[3] *= a[3];
    ov[e4] = v;
  }
}

extern "C" void kernel_launch(void* const* d_in, const int* in_sizes, int n_in,
                              void* d_out, int out_size, void* d_ws, size_t ws_size,
                              hipStream_t stream) {
  const float* x    = (const float*)d_in[0];
  const float* w    = (const float*)d_in[1];
  const float* bias = (const float*)d_in[2];
  float* out        = (float*)d_out;

  const size_t gpart_elems = (size_t)4 * 256 * 6400;       // 26.2 MB f32
  const size_t adj_elems   = (size_t)256 * 16640;          // 8.5 MB ushort
  const size_t s_elems     = (size_t)256 * 80;
  const size_t need = gpart_elems * 4 + adj_elems * 2 + s_elems * 4;

  if (ws_size >= need) {
    float* Gpart = (float*)d_ws;
    unsigned short* adjws = (unsigned short*)(Gpart + gpart_elems);
    float* s_ws = (float*)(adjws + adj_elems);
    k1_gram<<<4 * 256, 256, 0, stream>>>(x, Gpart);
    k2_adj<<<256, 256, 0, stream>>>(Gpart, adjws, s_ws);
    k3_gemm2<<<8 * 256, 256, 0, stream>>>(x, adjws, w, s_ws);
    k4_scale<<<8 * 256, 256, 0, stream>>>(x, s_ws, bias, out);
  } else {
    float* attn_ws = (float*)d_ws;
    scgcn_main_kernel<<<256, 512, 0, stream>>>(x, w, bias, attn_ws);
    scgcn_scale_kernel<<<256 * 8, 256, 0, stream>>>(x, attn_ws, out);
  }
}